// Round 2
// baseline (365.557 us; speedup 1.0000x reference)
//
#include <hip/hip_runtime.h>

#define NROW 160000
#define Nn 10000
#define NSTRIPE 1250  // NROW / 128
#define GRID 256

typedef __attribute__((ext_vector_type(8))) short short8;
typedef __attribute__((ext_vector_type(4))) float float4v;

__device__ __forceinline__ short f2bf(float f) {
  unsigned u = __builtin_bit_cast(unsigned, f);
  u = (u + 0x7FFFu + ((u >> 16) & 1u)) >> 16;
  return (short)u;
}

// pack two fp32 -> one u32 of two bf16 (RNE), low = a, high = b
__device__ __forceinline__ unsigned f2bf2(float a, float b) {
  unsigned ua = __builtin_bit_cast(unsigned, a);
  unsigned ub = __builtin_bit_cast(unsigned, b);
  ua = (ua + 0x7FFFu + ((ua >> 16) & 1u)) >> 16;
  ub = (ub + 0x7FFFu + ((ub >> 16) & 1u));
  return (ua & 0xFFFFu) | (ub & 0xFFFF0000u);
}

__device__ __forceinline__ short8 cvt8(float4 a, float4 b) {
  union { unsigned u[4]; short8 s; } r;
  r.u[0] = f2bf2(a.x, a.y);
  r.u[1] = f2bf2(a.z, a.w);
  r.u[2] = f2bf2(b.x, b.y);
  r.u[3] = f2bf2(b.z, b.w);
  return r.s;
}

// Wv [k=256][n=256] fp32 -> bt [n][k] bf16 (tiny, one-shot)
__global__ __launch_bounds__(256) void prep_k(const float* __restrict__ Wv,
                                              short* __restrict__ bt) {
  const int n = blockIdx.x, k = threadIdx.x;
  bt[n * 256 + k] = f2bf(Wv[k * 256 + n]);
}

// Persistent GEMM+LN: 256 blocks x 512 threads, exactly 1 block/CU (128 KB LDS).
// Whole B (256x256 bf16) staged in LDS ONCE per block, 16B-granule XOR-swizzled
// so ds_read_b128 across 16 n-rows is bank-conflict-free. Zero barriers in the
// main loop: wave (g,h) owns rows 64g..64g+63 x head h (cols 64h..64h+63) of
// each 128-row stripe; A fragments read from x into regs (depth-2 prefetch),
// per-head LayerNorm in-wave, scatter-store to final layout.
__global__ __launch_bounds__(512, 2) void gemm_ln(const float* __restrict__ x,
                                                  const short* __restrict__ bt,
                                                  const float* __restrict__ gamma,
                                                  const float* __restrict__ beta,
                                                  float* __restrict__ out) {
  __shared__ short blds[65536];  // [n=256][granule g'=32][8], g' = g ^ (n&7)
  const int t = threadIdx.x;
  const int w = t >> 6;
  const int gHalf = w >> 2;  // row half within stripe (0..1)
  const int h = w & 3;       // head (col block of 64)
  const int l = t & 63;
  const int r = l & 15;      // MFMA row/col-within-16 index
  const int q = l >> 4;      // MFMA k-quarter
  const int xk = r & 7;      // LDS xor key

  // first x prefetch (chunks 0,1 of first stripe) issued before staging so
  // HBM latency overlaps the B stage.
  float4 xa[3][4][2];
  int s = blockIdx.x;
  auto LOADX = [&](int sm, int cc, float4 (*dst)[2]) {
    const float* p = x + (size_t)(sm * 128 + gHalf * 64 + r) * 256 + cc * 32 + q * 8;
#pragma unroll
    for (int i = 0; i < 4; ++i) {
      dst[i][0] = *(const float4*)(p + i * 4096);
      dst[i][1] = *(const float4*)(p + i * 4096 + 4);
    }
  };
  LOADX(s, 0, xa[0]);
  LOADX(s, 1, xa[1]);

  // one-time B stage: bt[n][8g..8g+7] -> blds[n*256 + ((g^(n&7))<<3)]
  for (int i = t; i < 256 * 32; i += 512) {
    const int n = i >> 5, gr = i & 31;
    const int4 v = *(const int4*)(bt + n * 256 + gr * 8);
    *(int4*)&blds[n * 256 + ((gr ^ (n & 7)) << 3)] = v;
  }
  __syncthreads();  // only barrier in the kernel

  float gm[4], be[4];
#pragma unroll
  for (int j = 0; j < 4; ++j) {
    gm[j] = gamma[j * 16 + r];
    be[j] = beta[j * 16 + r];
  }

  const short* bfb = blds + (h * 64 + r) * 256;
  const int q4 = q * 4;

  for (; s < NSTRIPE; s += GRID) {
    float4v acc[4][4];
#pragma unroll
    for (int i = 0; i < 4; ++i)
#pragma unroll
      for (int j = 0; j < 4; ++j) acc[i][j] = (float4v){0.f, 0.f, 0.f, 0.f};

#pragma unroll
    for (int cc = 0; cc < 8; ++cc) {
      if (cc < 6) LOADX(s, cc + 2, xa[(cc + 2) % 3]);  // depth-2 prefetch
      short8 af[4], bf[4];
#pragma unroll
      for (int i = 0; i < 4; ++i)
        af[i] = cvt8(xa[cc % 3][i][0], xa[cc % 3][i][1]);
#pragma unroll
      for (int j = 0; j < 4; ++j)
        bf[j] = *(const short8*)&bfb[j * 4096 + (((cc * 4 + q) ^ xk) << 3)];
#pragma unroll
      for (int i = 0; i < 4; ++i)
#pragma unroll
        for (int j = 0; j < 4; ++j)
          acc[i][j] = __builtin_amdgcn_mfma_f32_16x16x32_bf16(af[i], bf[j],
                                                              acc[i][j], 0, 0, 0);
    }

    // cross-stripe prefetch before the epilogue (hides next stripe's latency)
    if (s + GRID < NSTRIPE) {
      LOADX(s + GRID, 0, xa[0]);
      LOADX(s + GRID, 1, xa[1]);
    }

    // per-head LayerNorm + scatter. C/D: col = r (within 16), row = q*4 + reg.
    const int m0 = s * 128 + gHalf * 64;
#pragma unroll
    for (int i = 0; i < 4; ++i) {
#pragma unroll
      for (int reg = 0; reg < 4; ++reg) {
        float s1 = acc[i][0][reg] + acc[i][1][reg] + acc[i][2][reg] + acc[i][3][reg];
        float s2 = acc[i][0][reg] * acc[i][0][reg] + acc[i][1][reg] * acc[i][1][reg] +
                   acc[i][2][reg] * acc[i][2][reg] + acc[i][3][reg] * acc[i][3][reg];
        s1 += __shfl_xor(s1, 1); s2 += __shfl_xor(s2, 1);
        s1 += __shfl_xor(s1, 2); s2 += __shfl_xor(s2, 2);
        s1 += __shfl_xor(s1, 4); s2 += __shfl_xor(s2, 4);
        s1 += __shfl_xor(s1, 8); s2 += __shfl_xor(s2, 8);
        const float mu = s1 * (1.f / 64.f);
        const float var = s2 * (1.f / 64.f) - mu * mu;
        const float inv = rsqrtf(var + 1e-5f);
        const int m = m0 + i * 16 + q4 + reg;
        const int b = m / Nn;
        const int n = m - b * Nn;
        const size_t obase = (size_t)(n & 15) * 2560000u +
                             (size_t)(b * 625 + (n >> 4)) * 256u + h * 64 + r;
#pragma unroll
        for (int j = 0; j < 4; ++j)
          out[obase + j * 16] = (acc[i][j][reg] - mu) * inv * gm[j] + be[j];
      }
    }
  }
}

extern "C" void kernel_launch(void* const* d_in, const int* in_sizes, int n_in,
                              void* d_out, int out_size, void* d_ws, size_t ws_size,
                              hipStream_t stream) {
  const float* x = (const float*)d_in[0];
  const float* Wv = (const float*)d_in[4];
  const float* gamma = (const float*)d_in[5];
  const float* beta = (const float*)d_in[6];
  float* out = (float*)d_out;
  short* wv_bt = (short*)d_ws;  // 256*256 bf16 = 128 KB

  prep_k<<<256, 256, 0, stream>>>(Wv, wv_bt);
  gemm_ln<<<GRID, 512, 0, stream>>>(x, wv_bt, gamma, beta, out);
}

// Round 3
// 309.114 us; speedup vs baseline: 1.1826x; 1.1826x over previous
//
#include <hip/hip_runtime.h>

#define Mm 160000
#define Nn 10000

typedef __attribute__((ext_vector_type(8))) short short8;
typedef __attribute__((ext_vector_type(4))) float float4v;

__device__ __forceinline__ short f2bf(float f) {
  // round-to-nearest-even fp32 -> bf16 (inputs are finite, no NaN handling)
  unsigned u = __builtin_bit_cast(unsigned, f);
  u = (u + 0x7FFFu + ((u >> 16) & 1u)) >> 16;
  return (short)u;
}

// pack two fp32 -> one u32 of two bf16 (RNE), low = a, high = b
__device__ __forceinline__ unsigned f2bf2(float a, float b) {
  unsigned ua = __builtin_bit_cast(unsigned, a);
  unsigned ub = __builtin_bit_cast(unsigned, b);
  ua = (ua + 0x7FFFu + ((ua >> 16) & 1u)) >> 16;
  ub = (ub + 0x7FFFu + ((ub >> 16) & 1u));
  return (ua & 0xFFFFu) | (ub & 0xFFFF0000u);
}

// Wv [k=256][n=256] fp32 -> bt [n][k] bf16 (tiny, one-shot)
__global__ __launch_bounds__(256) void prep_k(const float* __restrict__ Wv,
                                              short* __restrict__ bt) {
  const int n = blockIdx.x, k = threadIdx.x;
  bt[n * 256 + k] = f2bf(Wv[k * 256 + n]);
}

// R0 structure (best measured: 100 us), LDS cut 46->40 KB via 16B-granule XOR
// swizzle instead of +8 pads -> exactly 4 blocks/CU (16 waves/CU, +33% TLP).
// One block = 64 rows x 256 cols of v = x@Wv, K=256, staged in K=64 steps.
// Wave w (0..3) owns head w (cols 64w..64w+63) -> per-head LayerNorm in-wave.
// Swizzle: 16B granule g of row r stored at g^(r&7); bank base 4*(g^(r&7))
// gives the same 2-way-max conflict pattern as the old pads on stage writes
// and ds_read_b128 fragment reads.
__global__ __launch_bounds__(256, 4) void gemm_ln(const float* __restrict__ x,
                                                  const short* __restrict__ bt,
                                                  const float* __restrict__ gamma,
                                                  const float* __restrict__ beta,
                                                  float* __restrict__ out) {
  __shared__ short A[64][64];    // 8 KB, swizzled
  __shared__ short Bt[256][64];  // 32 KB, swizzled
  const int t = threadIdx.x;
  const int m0 = blockIdx.x * 64;
  const int w = t >> 6;   // wave = head
  const int l = t & 63;
  const int c16 = l & 15;
  const int q = l >> 4;
  const int xk = c16 & 7;  // frag-read xor key (row = ..16*i + c16, 16 = 0 mod 8)

  float4v acc[4][4];
#pragma unroll
  for (int i = 0; i < 4; ++i)
#pragma unroll
    for (int j = 0; j < 4; ++j) acc[i][j] = (float4v){0.f, 0.f, 0.f, 0.f};

  const int srow = t >> 3;      // staging: 8 lanes cover one 64-k row (32B each)
  const int sg = t & 7;         // 16B granule within row
  const int skey = srow & 7;    // stage xor key (row+32 has same key)

  for (int k0 = 0; k0 < 256; k0 += 64) {
    __syncthreads();
    // stage A: 64 rows x 64 k, fp32 global -> bf16 LDS (x read exactly once)
#pragma unroll
    for (int j = 0; j < 2; ++j) {
      const float* p = x + (size_t)(m0 + srow + j * 32) * 256 + k0 + sg * 8;
      const float4 a = *(const float4*)p;
      const float4 b = *(const float4*)(p + 4);
      union { unsigned u[4]; short8 s8; } r;
      r.u[0] = f2bf2(a.x, a.y); r.u[1] = f2bf2(a.z, a.w);
      r.u[2] = f2bf2(b.x, b.y); r.u[3] = f2bf2(b.z, b.w);
      *(short8*)&A[srow + j * 32][(sg ^ skey) << 3] = r.s8;
    }
    // stage Bt: 256 n-rows x 64 k bf16 (L2-resident, 16B loads)
#pragma unroll
    for (int j = 0; j < 8; ++j) {
      const int n = srow + j * 32;
      const int4 v = *(const int4*)(bt + (size_t)n * 256 + k0 + sg * 8);
      *(int4*)&Bt[n][(sg ^ skey) << 3] = v;
    }
    __syncthreads();
#pragma unroll
    for (int c = 0; c < 2; ++c) {  // two K=32 chunks
      short8 af[4], bf[4];
      const int gidx = ((c * 4 + q) ^ xk) << 3;
#pragma unroll
      for (int i = 0; i < 4; ++i)
        af[i] = *(const short8*)&A[i * 16 + c16][gidx];
#pragma unroll
      for (int j = 0; j < 4; ++j)
        bf[j] = *(const short8*)&Bt[w * 64 + j * 16 + c16][gidx];
#pragma unroll
      for (int i = 0; i < 4; ++i)
#pragma unroll
        for (int j = 0; j < 4; ++j)
          acc[i][j] = __builtin_amdgcn_mfma_f32_16x16x32_bf16(af[i], bf[j],
                                                              acc[i][j], 0, 0, 0);
    }
  }

  // Epilogue: per-head LayerNorm + scatter.
  // C/D layout: col = l&15 (within 16-tile), row = (l>>4)*4 + reg.
  float g[4], be[4];
#pragma unroll
  for (int j = 0; j < 4; ++j) {
    g[j] = gamma[j * 16 + c16];
    be[j] = beta[j * 16 + c16];
  }
  const int q4 = q * 4;
#pragma unroll
  for (int i = 0; i < 4; ++i) {
#pragma unroll
    for (int reg = 0; reg < 4; ++reg) {
      float s1 = acc[i][0][reg] + acc[i][1][reg] + acc[i][2][reg] + acc[i][3][reg];
      float s2 = acc[i][0][reg] * acc[i][0][reg] + acc[i][1][reg] * acc[i][1][reg] +
                 acc[i][2][reg] * acc[i][2][reg] + acc[i][3][reg] * acc[i][3][reg];
      s1 += __shfl_xor(s1, 1); s2 += __shfl_xor(s2, 1);
      s1 += __shfl_xor(s1, 2); s2 += __shfl_xor(s2, 2);
      s1 += __shfl_xor(s1, 4); s2 += __shfl_xor(s2, 4);
      s1 += __shfl_xor(s1, 8); s2 += __shfl_xor(s2, 8);
      const float mu = s1 * (1.f / 64.f);
      const float var = s2 * (1.f / 64.f) - mu * mu;
      const float inv = rsqrtf(var + 1e-5f);
      const int m = m0 + i * 16 + q4 + reg;
      const int b = m / Nn;
      const int n = m - b * Nn;
      const size_t obase = (size_t)(n & 15) * 2560000u +
                           (size_t)(b * 625 + (n >> 4)) * 256u + w * 64 + c16;
#pragma unroll
      for (int j = 0; j < 4; ++j)
        out[obase + j * 16] = (acc[i][j][reg] - mu) * inv * g[j] + be[j];
    }
  }
}

extern "C" void kernel_launch(void* const* d_in, const int* in_sizes, int n_in,
                              void* d_out, int out_size, void* d_ws, size_t ws_size,
                              hipStream_t stream) {
  const float* x = (const float*)d_in[0];
  const float* Wv = (const float*)d_in[4];
  const float* gamma = (const float*)d_in[5];
  const float* beta = (const float*)d_in[6];
  float* out = (float*)d_out;
  short* wv_bt = (short*)d_ws;  // 256*256 bf16 = 128 KB

  prep_k<<<256, 256, 0, stream>>>(Wv, wv_bt);
  gemm_ln<<<Mm / 64, 256, 0, stream>>>(x, wv_bt, gamma, beta, out);
}

// Round 4
// 305.294 us; speedup vs baseline: 1.1974x; 1.0125x over previous
//
#include <hip/hip_runtime.h>

#define Mm 160000
#define Nn 10000

typedef __attribute__((ext_vector_type(8))) short short8;
typedef __attribute__((ext_vector_type(4))) float float4v;

__device__ __forceinline__ short f2bf(float f) {
  // round-to-nearest-even fp32 -> bf16 (inputs are finite, no NaN handling)
  unsigned u = __builtin_bit_cast(unsigned, f);
  u = (u + 0x7FFFu + ((u >> 16) & 1u)) >> 16;
  return (short)u;
}

// pack two fp32 -> one u32 of two bf16 (RNE), low = a, high = b
__device__ __forceinline__ unsigned f2bf2(float a, float b) {
  unsigned ua = __builtin_bit_cast(unsigned, a);
  unsigned ub = __builtin_bit_cast(unsigned, b);
  ua = (ua + 0x7FFFu + ((ua >> 16) & 1u)) >> 16;
  ub = (ub + 0x7FFFu + ((ub >> 16) & 1u));
  return (ua & 0xFFFFu) | (ub & 0xFFFF0000u);
}

__device__ __forceinline__ void gload_lds16(const void* g, void* l) {
  __builtin_amdgcn_global_load_lds(
      (const __attribute__((address_space(1))) unsigned*)g,
      (__attribute__((address_space(3))) unsigned*)l, 16, 0, 0);
}

// Wv [k=256][n=256] fp32 -> bt [n][k] bf16, PRE-SWIZZLED per 64-k slice:
// bt[n][s*64 + g*8 + e] = bf16(Wv[s*64 + (g^(n&7))*8 + e][n]).
// gemm_ln stages bt linearly into LDS via global_load_lds; the linear copy
// then reproduces R3's verified 0-conflict XOR layout (rule: linear dest +
// inverse-swizzled source + XOR on read).
__global__ __launch_bounds__(256) void prep_k(const float* __restrict__ Wv,
                                              short* __restrict__ bt) {
  const int n = blockIdx.x, k = threadIdx.x;
  const int ksrc = (k & 0xC7) | ((((k >> 3) ^ n) & 7) << 3);
  bt[n * 256 + k] = f2bf(Wv[ksrc * 256 + n]);
}

// R0 structure: one block = 64 rows x 256 cols of v = x@Wv, K staged in 64-wide
// steps; wave w = head w -> per-head LayerNorm in-wave. Changes vs R0/R3:
//  - B staged with async global_load_lds (no VGPR round-trip, no ds_writes)
//  - raw s_barrier pair per K-step: stage-barrier drains vmcnt(0)+lgkmcnt(0);
//    compute-side tail barrier drains NOTHING, so next step's A prefetch
//    (registers only) stays in flight across it.
//  - no register cap (R3's 64-VGPR squeeze serialized staging).
__global__ __launch_bounds__(256) void gemm_ln(const float* __restrict__ x,
                                               const short* __restrict__ bt,
                                               const float* __restrict__ gamma,
                                               const float* __restrict__ beta,
                                               float* __restrict__ out) {
  __shared__ short A[64][64];    // 8 KB, XOR-swizzled 16B granules
  __shared__ short Bt[256][64];  // 32 KB, swizzled content via pre-swizzled bt
  const int t = threadIdx.x;
  const int m0 = blockIdx.x * 64;
  const int w = t >> 6;   // wave = head
  const int l = t & 63;
  const int c16 = l & 15;
  const int q = l >> 4;
  const int xk = c16 & 7;  // frag-read xor key (rows = 16*i + c16, 16 == 0 mod 8)

  float4v acc[4][4];
#pragma unroll
  for (int i = 0; i < 4; ++i)
#pragma unroll
    for (int j = 0; j < 4; ++j) acc[i][j] = (float4v){0.f, 0.f, 0.f, 0.f};

  // A staging: 8 lanes cover one 64-k row (32B each), rows srow and srow+32
  const int srow = t >> 3, sg = t & 7;
  const int skey = srow & 7;  // srow+32 has the same key
  const float* xbase = x + (size_t)(m0 + srow) * 256 + sg * 8;

  // B staging via gl_lds: wave w, call j covers LDS rows (j*4+w)*8..+8;
  // lane l -> row +(l>>3), granule l&7 (linear; content pre-swizzled in bt).
  const short* bsrc = bt + (size_t)(l >> 3) * 256 + (l & 7) * 8;

  // prologue: A(0) register prefetch
  float4 xa[2][2];
#pragma unroll
  for (int j = 0; j < 2; ++j) {
    xa[j][0] = *(const float4*)(xbase + j * 8192);
    xa[j][1] = *(const float4*)(xbase + j * 8192 + 4);
  }

#pragma unroll
  for (int k0i = 0; k0i < 4; ++k0i) {
    const int k0 = k0i * 64;
    // ---- stage phase ----
    // issue async B loads first (L2 latency hides under A cvt/ds_write)
#pragma unroll
    for (int j = 0; j < 8; ++j)
      gload_lds16(bsrc + (size_t)(j * 4 + w) * 2048 + k0, &Bt[(j * 4 + w) * 8][0]);
    // convert + write A from prefetched regs
#pragma unroll
    for (int j = 0; j < 2; ++j) {
      union { unsigned u[4]; short8 s8; } r;
      r.u[0] = f2bf2(xa[j][0].x, xa[j][0].y);
      r.u[1] = f2bf2(xa[j][0].z, xa[j][0].w);
      r.u[2] = f2bf2(xa[j][1].x, xa[j][1].y);
      r.u[3] = f2bf2(xa[j][1].z, xa[j][1].w);
      *(short8*)&A[srow + j * 32][(sg ^ skey) << 3] = r.s8;
    }
    // stage barrier: drain B gl_lds + A ds_writes (next A prefetch not yet
    // issued, so nothing useful is killed here)
    asm volatile("s_waitcnt vmcnt(0) lgkmcnt(0)\ns_barrier" ::: "memory");
    // A prefetch for next step — crosses the tail barrier below in flight
    if (k0i < 3) {
#pragma unroll
      for (int j = 0; j < 2; ++j) {
        xa[j][0] = *(const float4*)(xbase + j * 8192 + k0 + 64);
        xa[j][1] = *(const float4*)(xbase + j * 8192 + k0 + 68);
      }
    }
    // ---- compute phase ----
#pragma unroll
    for (int c = 0; c < 2; ++c) {  // two K=32 chunks
      short8 af[4], bf[4];
      const int gidx = ((c * 4 + q) ^ xk) << 3;
#pragma unroll
      for (int i = 0; i < 4; ++i)
        af[i] = *(const short8*)&A[i * 16 + c16][gidx];
#pragma unroll
      for (int j = 0; j < 4; ++j)
        bf[j] = *(const short8*)&Bt[w * 64 + j * 16 + c16][gidx];
#pragma unroll
      for (int i = 0; i < 4; ++i)
#pragma unroll
        for (int j = 0; j < 4; ++j)
          acc[i][j] = __builtin_amdgcn_mfma_f32_16x16x32_bf16(af[i], bf[j],
                                                              acc[i][j], 0, 0, 0);
    }
    // tail barrier: NO drain — every ds_read above has its MFMA consumer
    // before this point; only the A prefetch (register targets) is in flight.
    if (k0i < 3) asm volatile("s_barrier" ::: "memory");
  }

  // Epilogue: per-head LayerNorm + scatter.
  // C/D layout: col = l&15 (within 16-tile), row = (l>>4)*4 + reg.
  float g[4], be[4];
#pragma unroll
  for (int j = 0; j < 4; ++j) {
    g[j] = gamma[j * 16 + c16];
    be[j] = beta[j * 16 + c16];
  }
  const int q4 = q * 4;
#pragma unroll
  for (int i = 0; i < 4; ++i) {
#pragma unroll
    for (int reg = 0; reg < 4; ++reg) {
      float s1 = acc[i][0][reg] + acc[i][1][reg] + acc[i][2][reg] + acc[i][3][reg];
      float s2 = acc[i][0][reg] * acc[i][0][reg] + acc[i][1][reg] * acc[i][1][reg] +
                 acc[i][2][reg] * acc[i][2][reg] + acc[i][3][reg] * acc[i][3][reg];
      s1 += __shfl_xor(s1, 1); s2 += __shfl_xor(s2, 1);
      s1 += __shfl_xor(s1, 2); s2 += __shfl_xor(s2, 2);
      s1 += __shfl_xor(s1, 4); s2 += __shfl_xor(s2, 4);
      s1 += __shfl_xor(s1, 8); s2 += __shfl_xor(s2, 8);
      const float mu = s1 * (1.f / 64.f);
      const float var = s2 * (1.f / 64.f) - mu * mu;
      const float inv = rsqrtf(var + 1e-5f);
      const int m = m0 + i * 16 + q4 + reg;
      const int b = m / Nn;
      const int n = m - b * Nn;
      const size_t obase = (size_t)(n & 15) * 2560000u +
                           (size_t)(b * 625 + (n >> 4)) * 256u + w * 64 + c16;
#pragma unroll
      for (int j = 0; j < 4; ++j)
        out[obase + j * 16] = (acc[i][j][reg] - mu) * inv * g[j] + be[j];
    }
  }
}

extern "C" void kernel_launch(void* const* d_in, const int* in_sizes, int n_in,
                              void* d_out, int out_size, void* d_ws, size_t ws_size,
                              hipStream_t stream) {
  const float* x = (const float*)d_in[0];
  const float* Wv = (const float*)d_in[4];
  const float* gamma = (const float*)d_in[5];
  const float* beta = (const float*)d_in[6];
  float* out = (float*)d_out;
  short* wv_bt = (short*)d_ws;  // 256*256 bf16 = 128 KB

  prep_k<<<256, 256, 0, stream>>>(Wv, wv_bt);
  gemm_ln<<<Mm / 64, 256, 0, stream>>>(x, wv_bt, gamma, beta, out);
}